// Round 17
// baseline (854.153 us; speedup 1.0000x reference)
//
#include <hip/hip_runtime.h>
#include <hip/hip_bf16.h>

// SparseMoE: x[8,1024,1024] fp32, router[1024,8], w1[8,1024,4096], b1, w2[8,4096,1024], b2.
// Pipeline: router -> scan (offsets + 128/256 tile maps) -> assign -> copy ->
// transpose w1 -> GEMM1 (256^2 8-wave 8-phase counted-vmcnt dbuf, fast-GELU -> h bf16)
// -> transpose w2 -> GEMM2 (128^2 4-wave single-buf r14 structure, atomicAdd into out).

#define TT 8192
#define DD 1024
#define HH 4096
#define NE 8
#define NPAIR (TT * 2)           // 16384
#define PADROWS 256
#define MBLK (NPAIR / 128 + NE)  // 136: max 128-row tiles
#define MBLK2 (NPAIR / 256 + NE) // 72: max 256-row tiles

typedef __attribute__((ext_vector_type(4))) float f32x4;
typedef __attribute__((ext_vector_type(8))) short short8;
typedef __attribute__((ext_vector_type(4))) unsigned short u16x4;

__device__ __forceinline__ unsigned short bf16rne(float f) {
  union { float f; unsigned u; } v; v.f = f;
  unsigned r = v.u + 0x7FFFu + ((v.u >> 16) & 1u);
  return (unsigned short)(r >> 16);
}

// tanh-form GELU (|err| <= ~3e-3 vs exact; invisible under bf16 h + GEMM2 contraction)
__device__ __forceinline__ float gelu_fast(float x) {
  float y = 0.7978845608028654f * (x + 0.044715f * x * x * x);
  float e = __expf(2.0f * y);
  float th = 1.0f - 2.0f / (e + 1.0f);
  return 0.5f * x * (1.0f + th);
}

// 16B-granule swizzle within a [rows][8-granule] LDS tile; involution.
#define SWZ(r, kb) ((kb) ^ (((r) + ((r) >> 3)) & 7))

// hdr ints: [0..7] counts, [8..15] fill, [16..24] offsets, [25] tcnt128, [26] tcnt256,
// [32..167] te128, [168..303] tr128, [512..583] te256, [640..711] tr256
#define HDR_OFFS 16
#define HDR_TCNT 25
#define HDR_TCNT2 26
#define HDR_TE   32
#define HDR_TR   168
#define HDR2_TE  512
#define HDR2_TR  640

// ---------------- router: logits (fp64 accum), softmax-top2, counts ----------------
__global__ __launch_bounds__(256) void router_kernel(
    const float* __restrict__ x, const float* __restrict__ rw,
    int* __restrict__ hdr, int* __restrict__ te, float* __restrict__ tw)
{
  int t = blockIdx.x * 4 + (threadIdx.x >> 6);
  int lane = threadIdx.x & 63;
  const float* xr = x + (size_t)t * DD;
  double acc[NE];
#pragma unroll
  for (int e = 0; e < NE; ++e) acc[e] = 0.0;
  for (int i = 0; i < DD / 64; ++i) {
    int d = i * 64 + lane;
    float xv = xr[d];
    f32x4 r0 = *(const f32x4*)(rw + (size_t)d * NE);
    f32x4 r1 = *(const f32x4*)(rw + (size_t)d * NE + 4);
#pragma unroll
    for (int e = 0; e < 4; ++e) acc[e] += (double)xv * (double)r0[e];
#pragma unroll
    for (int e = 0; e < 4; ++e) acc[4 + e] += (double)xv * (double)r1[e];
  }
#pragma unroll
  for (int off = 32; off > 0; off >>= 1) {
#pragma unroll
    for (int e = 0; e < NE; ++e) acc[e] += __shfl_xor(acc[e], off);
  }
  if (lane == 0) {
    float l[NE];
#pragma unroll
    for (int e = 0; e < NE; ++e) l[e] = (float)acc[e];
    int bi = 0; float bv = l[0]; int si = -1; float sv = -3.0e38f;
#pragma unroll
    for (int e = 1; e < NE; ++e) {
      float v = l[e];
      if (v > bv) { sv = bv; si = bi; bv = v; bi = e; }
      else if (v > sv) { sv = v; si = e; }
    }
    float es = expf(sv - bv);
    float wb = 1.0f / (1.0f + es);
    float ws2 = es / (1.0f + es);
    te[2 * t] = bi; te[2 * t + 1] = si;
    tw[2 * t] = wb; tw[2 * t + 1] = ws2;
    atomicAdd(&hdr[bi], 1);
    atomicAdd(&hdr[si], 1);
  }
}

// ---------------- scan: offsets + both tile maps ----------------
__global__ void scan_kernel(int* __restrict__ hdr) {
  if (threadIdx.x == 0) {
    int s = 0;
#pragma unroll
    for (int e = 0; e < NE; ++e) { hdr[HDR_OFFS + e] = s; s += hdr[e]; }
    hdr[HDR_OFFS + NE] = s;
    int t = 0, t2 = 0;
    for (int e = 0; e < NE; ++e) {
      int cnt = hdr[e];
      for (int r = 0; r < cnt; r += 128) { hdr[HDR_TE + t] = e; hdr[HDR_TR + t] = r; ++t; }
      for (int r = 0; r < cnt; r += 256) { hdr[HDR2_TE + t2] = e; hdr[HDR2_TR + t2] = r; ++t2; }
    }
    hdr[HDR_TCNT] = t;
    hdr[HDR_TCNT2] = t2;
  }
  if (threadIdx.x < NE) hdr[8 + threadIdx.x] = 0;
}

// ---------------- assign: wave-aggregated slot allocation ----------------
__global__ __launch_bounds__(256) void assign_kernel(
    const int* __restrict__ te, const float* __restrict__ tw, int* __restrict__ hdr,
    int* __restrict__ pair_token, float* __restrict__ pair_w)
{
  int lane = threadIdx.x & 63;
  int t = blockIdx.x * 256 + threadIdx.x;
  int e0 = te[2 * t], e1 = te[2 * t + 1];
  const int* offs = hdr + HDR_OFFS;
  unsigned long long below = (1ull << lane) - 1ull;
  int slot0 = 0, slot1 = 0;
#pragma unroll
  for (int e = 0; e < NE; ++e) {
    unsigned long long m0 = __ballot(e0 == e);
    unsigned long long m1 = __ballot(e1 == e);
    int cnt = __popcll(m0) + __popcll(m1);
    int base = 0;
    if (lane == 0 && cnt) base = atomicAdd(&hdr[8 + e], cnt);
    base = __shfl(base, 0);
    int s = offs[e] + base;
    if (e0 == e) slot0 = s + __popcll(m0 & below);
    if (e1 == e) slot1 = s + __popcll(m0) + __popcll(m1 & below);
  }
  pair_token[slot0] = t; pair_w[slot0] = tw[2 * t];
  pair_token[slot1] = t; pair_w[slot1] = tw[2 * t + 1];
}

// ---------------- copy: one wave per pair, x[tok] f32 -> xg[pair] bf16 ----------------
__global__ __launch_bounds__(256) void copy_kernel(
    const float* __restrict__ x, const int* __restrict__ pair_token,
    unsigned short* __restrict__ xg)
{
  int p = (blockIdx.x * 256 + threadIdx.x) >> 6;
  int lane = threadIdx.x & 63;
  int tok = pair_token[p];
  const f32x4* xr = (const f32x4*)(x + (size_t)tok * DD);
  unsigned short* d = xg + (size_t)p * DD;
#pragma unroll
  for (int i = 0; i < 4; ++i) {
    int idx = i * 64 + lane;
    f32x4 v = xr[idx];
    u16x4 b;
#pragma unroll
    for (int j = 0; j < 4; ++j) b[j] = bf16rne(v[j]);
    *(u16x4*)(d + idx * 4) = b;
  }
}

// ---------------- transpose+convert: W[e][K][N] f32 -> WT[e][N][K] bf16 ----------------
__global__ __launch_bounds__(256) void transpose_bf16_kernel(
    const float* __restrict__ W, unsigned short* __restrict__ WT, int K, int N)
{
  __shared__ unsigned short t[64][72];
  const float* src = W + (size_t)blockIdx.z * K * N;
  unsigned short* dst = WT + (size_t)blockIdx.z * N * K;
  const int K0 = blockIdx.y * 64, N0 = blockIdx.x * 64;
  const int tid = threadIdx.x;
  const int c = (tid & 15) * 4;
#pragma unroll
  for (int p = 0; p < 4; ++p) {
    int r = (tid >> 4) + p * 16;
    f32x4 v = *(const f32x4*)(src + (size_t)(K0 + r) * N + N0 + c);
    u16x4 b;
#pragma unroll
    for (int j = 0; j < 4; ++j) b[j] = bf16rne(v[j]);
    *(u16x4*)&t[r][c] = b;
  }
  __syncthreads();
  const int n = tid >> 2;
  const int k0 = (tid & 3) * 16;
  __align__(16) unsigned short tmp[16];
#pragma unroll
  for (int i = 0; i < 16; ++i) tmp[i] = t[k0 + i][n];
  unsigned short* dp = dst + (size_t)(N0 + n) * K + K0 + k0;
  *(u16x4*)(dp + 0)  = *(u16x4*)(tmp + 0);
  *(u16x4*)(dp + 4)  = *(u16x4*)(tmp + 4);
  *(u16x4*)(dp + 8)  = *(u16x4*)(tmp + 8);
  *(u16x4*)(dp + 12) = *(u16x4*)(tmp + 12);
}

// ================= GEMM1: 256x256 tile, BK=64, 8 waves, 8-phase counted-vmcnt ========
// dbuf halves: per tile, 4 half-tiles {Bcols0, Bcols1, Arows0, Arows1} staged one per
// phase of the PREVIOUS tile. vmcnt(4) per phase => everything staged <= P-2 landed
// before this phase's ds_reads (issued after the barrier). 2 barriers/phase (WAR: a
// phase's ds_reads are consumed by its MFMA before its closing barrier; stages write
// the opposite dbuf). Prologue drains once; final tile drains at its p0.
template <bool DO_STAGE>
__device__ __forceinline__ void tile_phases(
    const unsigned short* Ab, const unsigned short* Bb,
    unsigned short* An, unsigned short* Bn,
    const unsigned short* Asrc, const unsigned short* Bsrc,
    int kt, int tid, int lane, int wr, int wc,
    f32x4 (&acc)[8][4], short8 (&bfr)[4])
{
  const int K = DD;
  const int k0n = (kt + 1) * 64;
#pragma unroll
  for (int P = 0; P < 4; ++P) {
    if (DO_STAGE) {
#pragma unroll
      for (int p2 = 0; p2 < 2; ++p2) {
        int s = p2 * 512 + tid;
        int rr = s >> 3, g = s & 7;
        if (P < 2) {
          int c = P * 128 + rr;
          __builtin_amdgcn_global_load_lds(
              (const __attribute__((address_space(1))) void*)(Bsrc + (size_t)c * K + k0n + SWZ(c, g) * 8),
              (__attribute__((address_space(3))) void*)(Bn + c * 64 + g * 8), 16, 0, 0);
        } else {
          int r = (P - 2) * 128 + rr;
          __builtin_amdgcn_global_load_lds(
              (const __attribute__((address_space(1))) void*)(Asrc + (size_t)r * K + k0n + SWZ(r, g) * 8),
              (__attribute__((address_space(3))) void*)(An + r * 64 + g * 8), 16, 0, 0);
        }
      }
      asm volatile("s_waitcnt vmcnt(4)" ::: "memory");
    } else {
      if (P == 0) asm volatile("s_waitcnt vmcnt(0)" ::: "memory");
    }
    __builtin_amdgcn_s_barrier();
    const int ks = P >> 1, mh = P & 1;
    const int kq = ks * 4 + (lane >> 4);
    if (mh == 0) {
#pragma unroll
      for (int n = 0; n < 4; ++n) {
        int c = wc * 64 + n * 16 + (lane & 15);
        bfr[n] = *(const short8*)(Bb + c * 64 + SWZ(c, kq) * 8);
      }
    }
    short8 af[4];
#pragma unroll
    for (int i = 0; i < 4; ++i) {
      int row = wr * 128 + (mh * 4 + i) * 16 + (lane & 15);
      af[i] = *(const short8*)(Ab + row * 64 + SWZ(row, kq) * 8);
    }
    asm volatile("s_waitcnt lgkmcnt(0)" ::: "memory");
    __builtin_amdgcn_sched_barrier(0);
    __builtin_amdgcn_s_setprio(1);
#pragma unroll
    for (int i = 0; i < 4; ++i)
#pragma unroll
      for (int n = 0; n < 4; ++n)
        acc[mh * 4 + i][n] =
            __builtin_amdgcn_mfma_f32_16x16x32_bf16(af[i], bfr[n], acc[mh * 4 + i][n], 0, 0, 0);
    __builtin_amdgcn_s_setprio(0);
    __builtin_amdgcn_s_barrier();
  }
}

__global__ __launch_bounds__(512) void moe_gemm1_8ph(
    const unsigned short* __restrict__ Aall,   // xg
    const unsigned short* __restrict__ BT,     // w1T [E][N][K]
    const float* __restrict__ bias,
    const int* __restrict__ hdr,
    unsigned short* __restrict__ Hout)
{
  const int K = DD, N = HH;
  // XCD supertile decode: nwg = 72*16 = 1152; 144/XCD; supertile 4m x 4n
  const int orig = blockIdx.x + MBLK2 * blockIdx.y;
  const int xcd = orig & 7, loc = orig >> 3;
  const int idx = xcd * 144 + loc;
  const int st = idx >> 4, w = idx & 15;
  const int mx = (st % 18) * 4 + (w & 3);
  const int ny = (st / 18) * 4 + (w >> 2);

  if (mx >= hdr[HDR_TCNT2]) return;
  const int e = hdr[HDR2_TE + mx];
  const int r0 = hdr[HDR2_TR + mx];
  const int* offs = hdr + HDR_OFFS;
  const int row_base = offs[e];
  const int n_rows = offs[e + 1] - row_base;
  const int n0 = ny * 256;

  const unsigned short* Asrc = Aall + (size_t)(row_base + r0) * K;
  const unsigned short* Bsrc = BT + (size_t)e * N * K + (size_t)n0 * K;

  __shared__ __align__(16) unsigned short A0[256 * 64];
  __shared__ __align__(16) unsigned short B0[256 * 64];
  __shared__ __align__(16) unsigned short A1[256 * 64];
  __shared__ __align__(16) unsigned short B1[256 * 64];   // 128 KiB

  const int tid = threadIdx.x;
  const int lane = tid & 63;
  const int wv = tid >> 6;      // 0..7
  const int wr = wv >> 2;       // 0..1: 128-row half
  const int wc = wv & 3;        // 0..3: 64-col quarter

  f32x4 acc[8][4] = {};
  short8 bfr[4];

  // prologue: stage all 4 halves of tile 0 (order Bc0, Bc1, Ah0, Ah1); drain; barrier
#pragma unroll
  for (int H = 0; H < 4; ++H) {
#pragma unroll
    for (int p2 = 0; p2 < 2; ++p2) {
      int s = p2 * 512 + tid;
      int rr = s >> 3, g = s & 7;
      if (H < 2) {
        int c = H * 128 + rr;
        __builtin_amdgcn_global_load_lds(
            (const __attribute__((address_space(1))) void*)(Bsrc + (size_t)c * K + SWZ(c, g) * 8),
            (__attribute__((address_space(3))) void*)(B0 + c * 64 + g * 8), 16, 0, 0);
      } else {
        int r = (H - 2) * 128 + rr;
        __builtin_amdgcn_global_load_lds(
            (const __attribute__((address_space(1))) void*)(Asrc + (size_t)r * K + SWZ(r, g) * 8),
            (__attribute__((address_space(3))) void*)(A0 + r * 64 + g * 8), 16, 0, 0);
      }
    }
  }
  asm volatile("s_waitcnt vmcnt(0)" ::: "memory");
  __builtin_amdgcn_s_barrier();

  // NT = K/64 = 16 tiles; dbuf ping-pong with named buffers; last tile drains.
#pragma unroll 1
  for (int t = 0; t < 14; t += 2) {
    tile_phases<true>(A0, B0, A1, B1, Asrc, Bsrc, t,     tid, lane, wr, wc, acc, bfr);
    tile_phases<true>(A1, B1, A0, B0, Asrc, Bsrc, t + 1, tid, lane, wr, wc, acc, bfr);
  }
  tile_phases<true >(A0, B0, A1, B1, Asrc, Bsrc, 14, tid, lane, wr, wc, acc, bfr);
  tile_phases<false>(A1, B1, A0, B0, Asrc, Bsrc, 15, tid, lane, wr, wc, acc, bfr);

  // epilogue (C/D frag: col = lane&15, row = (lane>>4)*4 + reg)
#pragma unroll
  for (int m = 0; m < 8; ++m) {
#pragma unroll
    for (int j = 0; j < 4; ++j) {
      int gr = r0 + wr * 128 + m * 16 + (lane >> 4) * 4 + j;
      if (gr >= n_rows) continue;
#pragma unroll
      for (int n = 0; n < 4; ++n) {
        int gc = n0 + wc * 64 + n * 16 + (lane & 15);
        float v = acc[m][n][j] + bias[e * N + gc];
        Hout[(size_t)(row_base + gr) * N + gc] = bf16rne(gelu_fast(v));
      }
    }
  }
}

// ---------------- GEMM2: 128x128, BK=64, 4 waves, single-buf (r14 verbatim) --------
__global__ __launch_bounds__(256) void moe_gemm2(
    const unsigned short* __restrict__ Aall,   // h
    const unsigned short* __restrict__ BT,     // w2T [E][N][K]
    const float* __restrict__ bias,
    const int* __restrict__ hdr,
    const int* __restrict__ pair_token,
    const float* __restrict__ pair_w,
    float* __restrict__ out)
{
  const int K = HH, N = DD;
  const int XPB = (MBLK * (DD / 128)) / 8;   // 136
  const int orig = blockIdx.x + MBLK * blockIdx.y;
  const int xcd = orig & 7, loc = orig >> 3;
  const int idx = xcd * XPB + loc;
  const int st = idx >> 5, w = idx & 31;
  const int mx = (st % 17) * 8 + (w & 7);
  const int ny = (st / 17) * 4 + (w >> 3);

  if (mx >= hdr[HDR_TCNT]) return;
  const int e = hdr[HDR_TE + mx];
  const int r0 = hdr[HDR_TR + mx];
  const int* offs = hdr + HDR_OFFS;
  const int row_base = offs[e];
  const int n_rows = offs[e + 1] - row_base;
  const int n0 = ny * 128;

  const unsigned short* A = Aall + (size_t)row_base * K;
  const unsigned short* B = BT + (size_t)e * N * K;

  __shared__ __align__(16) unsigned short Asw[128 * 64];
  __shared__ __align__(16) unsigned short Bsw[128 * 64];

  const int tid = threadIdx.x;
  const int lane = tid & 63;
  const int wv = tid >> 6;
  const int wr = wv >> 1, wc = wv & 1;

  f32x4 acc[4][4] = {};

  for (int k0 = 0; k0 < K; k0 += 64) {
    if (k0) __syncthreads();
#pragma unroll
    for (int p = 0; p < 4; ++p) {
      int s = p * 256 + tid;
      int row = s >> 3;
      int kb = SWZ(row, s & 7);
      __builtin_amdgcn_global_load_lds(
          (const __attribute__((address_space(1))) void*)(A + (size_t)(r0 + row) * K + k0 + kb * 8),
          (__attribute__((address_space(3))) void*)(Asw + s * 8), 16, 0, 0);
    }
#pragma unroll
    for (int p = 0; p < 4; ++p) {
      int s = p * 256 + tid;
      int row = s >> 3;
      int kb = SWZ(row, s & 7);
      __builtin_amdgcn_global_load_lds(
          (const __attribute__((address_space(1))) void*)(B + (size_t)(n0 + row) * K + k0 + kb * 8),
          (__attribute__((address_space(3))) void*)(Bsw + s * 8), 16, 0, 0);
    }
    __syncthreads();
#pragma unroll
    for (int s2 = 0; s2 < 2; ++s2) {
      short8 af[4], bfr[4];
      int kq = s2 * 4 + (lane >> 4);
#pragma unroll
      for (int m = 0; m < 4; ++m) {
        int row = wr * 64 + m * 16 + (lane & 15);
        af[m] = *(const short8*)(Asw + row * 64 + SWZ(row, kq) * 8);
      }
#pragma unroll
      for (int n = 0; n < 4; ++n) {
        int c = wc * 64 + n * 16 + (lane & 15);
        bfr[n] = *(const short8*)(Bsw + c * 64 + SWZ(c, kq) * 8);
      }
#pragma unroll
      for (int m = 0; m < 4; ++m)
#pragma unroll
        for (int n = 0; n < 4; ++n)
          acc[m][n] = __builtin_amdgcn_mfma_f32_16x16x32_bf16(af[m], bfr[n], acc[m][n], 0, 0, 0);
    }
  }

#pragma unroll
  for (int m = 0; m < 4; ++m) {
#pragma unroll
    for (int j = 0; j < 4; ++j) {
      int gr = r0 + wr * 64 + m * 16 + (lane >> 4) * 4 + j;
      if (gr >= n_rows) continue;
      int tok = pair_token[row_base + gr];
      float w2 = pair_w[row_base + gr];
#pragma unroll
      for (int n = 0; n < 4; ++n) {
        int gc = n0 + wc * 64 + n * 16 + (lane & 15);
        float v = acc[m][n][j] + bias[e * N + gc];
        atomicAdd(&out[(size_t)tok * N + gc], w2 * v);
      }
    }
  }
}

extern "C" void kernel_launch(void* const* d_in, const int* in_sizes, int n_in,
                              void* d_out, int out_size, void* d_ws, size_t ws_size,
                              hipStream_t stream) {
  const float* x  = (const float*)d_in[0];
  const float* rw = (const float*)d_in[1];
  const float* w1 = (const float*)d_in[2];
  const float* b1 = (const float*)d_in[3];
  const float* w2 = (const float*)d_in[4];
  const float* b2 = (const float*)d_in[5];
  float* out = (float*)d_out;

  // ws layout: hdr 4KB | te,tw,pt,pw 4x64KB | xg bf16[(P+256)*D] |
  //            h bf16[(P+256)*H] | wT bf16[E*D*H] (shared by w1T then w2T)
  char* ws = (char*)d_ws;
  const size_t OFF_TE = 4096;
  const size_t OFF_TW = OFF_TE + (size_t)NPAIR * 4;
  const size_t OFF_PT = OFF_TW + (size_t)NPAIR * 4;
  const size_t OFF_PW = OFF_PT + (size_t)NPAIR * 4;
  const size_t OFF_XG = OFF_PW + (size_t)NPAIR * 4;
  const size_t OFF_H  = OFF_XG + (size_t)(NPAIR + PADROWS) * DD * 2;
  const size_t OFF_WT = OFF_H + (size_t)(NPAIR + PADROWS) * HH * 2;
  const size_t NEEDED = OFF_WT + (size_t)NE * DD * HH * 2;
  if (ws_size < NEEDED) return;  // visible failure signal (zero output)

  int*   hdr        = (int*)ws;
  int*   te         = (int*)(ws + OFF_TE);
  float* tw         = (float*)(ws + OFF_TW);
  int*   pair_token = (int*)(ws + OFF_PT);
  float* pair_w     = (float*)(ws + OFF_PW);
  unsigned short* xg = (unsigned short*)(ws + OFF_XG);
  unsigned short* h  = (unsigned short*)(ws + OFF_H);
  unsigned short* wT = (unsigned short*)(ws + OFF_WT);

  hipMemsetAsync(d_ws, 0, 4096, stream);
  hipMemsetAsync(d_out, 0, (size_t)out_size * sizeof(float), stream);

  router_kernel<<<TT / 4, 256, 0, stream>>>(x, rw, hdr, te, tw);
  scan_kernel<<<1, 64, 0, stream>>>(hdr);
  assign_kernel<<<TT / 256, 256, 0, stream>>>(te, tw, hdr, pair_token, pair_w);
  copy_kernel<<<NPAIR / 4, 256, 0, stream>>>(x, pair_token, xg);

  // w1[e][D][H] -> w1T[e][H][D]
  transpose_bf16_kernel<<<dim3(HH / 64, DD / 64, NE), 256, 0, stream>>>(w1, wT, DD, HH);
  // GEMM1 8-phase: grid 72 x 16 = 1152 blocks (144/XCD = 9 4x4 supertiles)
  moe_gemm1_8ph<<<dim3(MBLK2, HH / 256), 512, 0, stream>>>(xg, wT, b1, hdr, h);

  // w2[e][H][D] -> w2T[e][D][H]
  transpose_bf16_kernel<<<dim3(DD / 64, HH / 64, NE), 256, 0, stream>>>(w2, wT, HH, DD);
  // GEMM2: grid 136 x 8 = 1088 blocks (r14 structure)
  moe_gemm2<<<dim3(MBLK, DD / 128), 256, 0, stream>>>(
      h, wT, b2, hdr, pair_token, pair_w, out);
}

// Round 18
// 762.521 us; speedup vs baseline: 1.1202x; 1.1202x over previous
//
#include <hip/hip_runtime.h>
#include <hip/hip_bf16.h>

// SparseMoE: x[8,1024,1024] fp32, router[1024,8], w1[8,1024,4096], b1, w2[8,4096,1024], b2.
// Pipeline: router -> scan (offsets + tile map) -> assign -> copy ->
// transpose w1 -> GEMM1 (128^2 BK=64 single-buf, supertile XCD order, fast-GELU -> h bf16)
// -> transpose w2 -> GEMM2 (same structure, atomicAdd into out).
// [r14 configuration — session best 761 us; all in-block pipelining variants refuted 7/7]

#define TT 8192
#define DD 1024
#define HH 4096
#define NE 8
#define NPAIR (TT * 2)          // 16384
#define PADROWS 256
#define MBLK (NPAIR / 128 + NE) // 136: max 128-row tiles

typedef __attribute__((ext_vector_type(4))) float f32x4;
typedef __attribute__((ext_vector_type(8))) short short8;
typedef __attribute__((ext_vector_type(4))) unsigned short u16x4;

__device__ __forceinline__ unsigned short bf16rne(float f) {
  union { float f; unsigned u; } v; v.f = f;
  unsigned r = v.u + 0x7FFFu + ((v.u >> 16) & 1u);
  return (unsigned short)(r >> 16);
}

// tanh-form GELU (|err| <= ~3e-3 vs exact; invisible under bf16 h + GEMM2 contraction)
__device__ __forceinline__ float gelu_fast(float x) {
  float y = 0.7978845608028654f * (x + 0.044715f * x * x * x);
  float e = __expf(2.0f * y);
  float th = 1.0f - 2.0f / (e + 1.0f);
  return 0.5f * x * (1.0f + th);
}

// 16B-granule swizzle within a [rows][8-granule] LDS tile; involution.
#define SWZ(r, kb) ((kb) ^ (((r) + ((r) >> 3)) & 7))

// hdr ints: [0..7] counts, [8..15] fill, [16..24] offsets, [25] tcnt,
// [32..167] tile_e, [168..303] tile_r0
#define HDR_OFFS 16
#define HDR_TCNT 25
#define HDR_TE   32
#define HDR_TR   168

// ---------------- router: logits (fp64 accum), softmax-top2, counts ----------------
__global__ __launch_bounds__(256) void router_kernel(
    const float* __restrict__ x, const float* __restrict__ rw,
    int* __restrict__ hdr, int* __restrict__ te, float* __restrict__ tw)
{
  int t = blockIdx.x * 4 + (threadIdx.x >> 6);
  int lane = threadIdx.x & 63;
  const float* xr = x + (size_t)t * DD;
  double acc[NE];
#pragma unroll
  for (int e = 0; e < NE; ++e) acc[e] = 0.0;
  for (int i = 0; i < DD / 64; ++i) {
    int d = i * 64 + lane;
    float xv = xr[d];
    f32x4 r0 = *(const f32x4*)(rw + (size_t)d * NE);
    f32x4 r1 = *(const f32x4*)(rw + (size_t)d * NE + 4);
#pragma unroll
    for (int e = 0; e < 4; ++e) acc[e] += (double)xv * (double)r0[e];
#pragma unroll
    for (int e = 0; e < 4; ++e) acc[4 + e] += (double)xv * (double)r1[e];
  }
#pragma unroll
  for (int off = 32; off > 0; off >>= 1) {
#pragma unroll
    for (int e = 0; e < NE; ++e) acc[e] += __shfl_xor(acc[e], off);
  }
  if (lane == 0) {
    float l[NE];
#pragma unroll
    for (int e = 0; e < NE; ++e) l[e] = (float)acc[e];
    int bi = 0; float bv = l[0]; int si = -1; float sv = -3.0e38f;
#pragma unroll
    for (int e = 1; e < NE; ++e) {
      float v = l[e];
      if (v > bv) { sv = bv; si = bi; bv = v; bi = e; }
      else if (v > sv) { sv = v; si = e; }
    }
    float es = expf(sv - bv);
    float wb = 1.0f / (1.0f + es);
    float ws2 = es / (1.0f + es);
    te[2 * t] = bi; te[2 * t + 1] = si;
    tw[2 * t] = wb; tw[2 * t + 1] = ws2;
    atomicAdd(&hdr[bi], 1);
    atomicAdd(&hdr[si], 1);
  }
}

// ---------------- scan: offsets + M-tile map (tiles of 128 rows) ----------------
__global__ void scan_kernel(int* __restrict__ hdr) {
  if (threadIdx.x == 0) {
    int s = 0;
#pragma unroll
    for (int e = 0; e < NE; ++e) { hdr[HDR_OFFS + e] = s; s += hdr[e]; }
    hdr[HDR_OFFS + NE] = s;
    int t = 0;
    for (int e = 0; e < NE; ++e) {
      int cnt = hdr[e];
      for (int r = 0; r < cnt; r += 128) {
        hdr[HDR_TE + t] = e;
        hdr[HDR_TR + t] = r;
        ++t;
      }
    }
    hdr[HDR_TCNT] = t;
  }
  if (threadIdx.x < NE) hdr[8 + threadIdx.x] = 0;
}

// ---------------- assign: wave-aggregated slot allocation ----------------
__global__ __launch_bounds__(256) void assign_kernel(
    const int* __restrict__ te, const float* __restrict__ tw, int* __restrict__ hdr,
    int* __restrict__ pair_token, float* __restrict__ pair_w)
{
  int lane = threadIdx.x & 63;
  int t = blockIdx.x * 256 + threadIdx.x;
  int e0 = te[2 * t], e1 = te[2 * t + 1];
  const int* offs = hdr + HDR_OFFS;
  unsigned long long below = (1ull << lane) - 1ull;
  int slot0 = 0, slot1 = 0;
#pragma unroll
  for (int e = 0; e < NE; ++e) {
    unsigned long long m0 = __ballot(e0 == e);
    unsigned long long m1 = __ballot(e1 == e);
    int cnt = __popcll(m0) + __popcll(m1);
    int base = 0;
    if (lane == 0 && cnt) base = atomicAdd(&hdr[8 + e], cnt);
    base = __shfl(base, 0);
    int s = offs[e] + base;
    if (e0 == e) slot0 = s + __popcll(m0 & below);
    if (e1 == e) slot1 = s + __popcll(m0) + __popcll(m1 & below);
  }
  pair_token[slot0] = t; pair_w[slot0] = tw[2 * t];
  pair_token[slot1] = t; pair_w[slot1] = tw[2 * t + 1];
}

// ---------------- copy: one wave per pair, x[tok] f32 -> xg[pair] bf16 ----------------
__global__ __launch_bounds__(256) void copy_kernel(
    const float* __restrict__ x, const int* __restrict__ pair_token,
    unsigned short* __restrict__ xg)
{
  int p = (blockIdx.x * 256 + threadIdx.x) >> 6;
  int lane = threadIdx.x & 63;
  int tok = pair_token[p];
  const f32x4* xr = (const f32x4*)(x + (size_t)tok * DD);
  unsigned short* d = xg + (size_t)p * DD;
#pragma unroll
  for (int i = 0; i < 4; ++i) {
    int idx = i * 64 + lane;
    f32x4 v = xr[idx];
    u16x4 b;
#pragma unroll
    for (int j = 0; j < 4; ++j) b[j] = bf16rne(v[j]);
    *(u16x4*)(d + idx * 4) = b;
  }
}

// ---------------- transpose+convert: W[e][K][N] f32 -> WT[e][N][K] bf16 ----------------
__global__ __launch_bounds__(256) void transpose_bf16_kernel(
    const float* __restrict__ W, unsigned short* __restrict__ WT, int K, int N)
{
  __shared__ unsigned short t[64][72];
  const float* src = W + (size_t)blockIdx.z * K * N;
  unsigned short* dst = WT + (size_t)blockIdx.z * N * K;
  const int K0 = blockIdx.y * 64, N0 = blockIdx.x * 64;
  const int tid = threadIdx.x;
  const int c = (tid & 15) * 4;
#pragma unroll
  for (int p = 0; p < 4; ++p) {
    int r = (tid >> 4) + p * 16;
    f32x4 v = *(const f32x4*)(src + (size_t)(K0 + r) * N + N0 + c);
    u16x4 b;
#pragma unroll
    for (int j = 0; j < 4; ++j) b[j] = bf16rne(v[j]);
    *(u16x4*)&t[r][c] = b;
  }
  __syncthreads();
  const int n = tid >> 2;
  const int k0 = (tid & 3) * 16;
  __align__(16) unsigned short tmp[16];
#pragma unroll
  for (int i = 0; i < 16; ++i) tmp[i] = t[k0 + i][n];
  unsigned short* dp = dst + (size_t)(N0 + n) * K + K0 + k0;
  *(u16x4*)(dp + 0)  = *(u16x4*)(tmp + 0);
  *(u16x4*)(dp + 4)  = *(u16x4*)(tmp + 4);
  *(u16x4*)(dp + 8)  = *(u16x4*)(tmp + 8);
  *(u16x4*)(dp + 12) = *(u16x4*)(tmp + 12);
}

// ---------------- grouped GEMM body: 128x128, BK=64, 4 waves, single-buf --------
// Chunked-supertile XCD ordering: supertile = 8 m-tiles x 4 n-tiles = 32 blocks
// (A 2MB + B 1MB fits one XCD's 4MB L2); supertiles contiguous per XCD.
template <int ACT>
__device__ __forceinline__ void gemm_body(
    const unsigned short* __restrict__ Aall,
    const unsigned short* __restrict__ BT,
    const float* __restrict__ bias,
    const int* __restrict__ hdr,
    unsigned short* __restrict__ Hout,
    const int* __restrict__ pair_token,
    const float* __restrict__ pair_w,
    float* __restrict__ out,
    int K, int N, int XPB)
{
  const int orig = blockIdx.x + MBLK * blockIdx.y;
  const int xcd = orig & 7, loc = orig >> 3;
  const int idx = xcd * XPB + loc;
  const int st = idx >> 5, w = idx & 31;
  const int mx = (st % 17) * 8 + (w & 7);
  const int ny = (st / 17) * 4 + (w >> 3);

  if (mx >= hdr[HDR_TCNT]) return;
  const int e = hdr[HDR_TE + mx];
  const int r0 = hdr[HDR_TR + mx];
  const int* offs = hdr + HDR_OFFS;
  const int row_base = offs[e];
  const int n_rows = offs[e + 1] - row_base;
  const int n0 = ny * 128;

  const unsigned short* A = Aall + (size_t)row_base * K;
  const unsigned short* B = BT + (size_t)e * N * K;

  __shared__ __align__(16) unsigned short Asw[128 * 64];
  __shared__ __align__(16) unsigned short Bsw[128 * 64];

  const int tid = threadIdx.x;
  const int lane = tid & 63;
  const int wv = tid >> 6;
  const int wr = wv >> 1, wc = wv & 1;

  f32x4 acc[4][4] = {};

  for (int k0 = 0; k0 < K; k0 += 64) {
    if (k0) __syncthreads();
#pragma unroll
    for (int p = 0; p < 4; ++p) {
      int s = p * 256 + tid;
      int row = s >> 3;
      int kb = SWZ(row, s & 7);
      __builtin_amdgcn_global_load_lds(
          (const __attribute__((address_space(1))) void*)(A + (size_t)(r0 + row) * K + k0 + kb * 8),
          (__attribute__((address_space(3))) void*)(Asw + s * 8), 16, 0, 0);
    }
#pragma unroll
    for (int p = 0; p < 4; ++p) {
      int s = p * 256 + tid;
      int row = s >> 3;
      int kb = SWZ(row, s & 7);
      __builtin_amdgcn_global_load_lds(
          (const __attribute__((address_space(1))) void*)(B + (size_t)(n0 + row) * K + k0 + kb * 8),
          (__attribute__((address_space(3))) void*)(Bsw + s * 8), 16, 0, 0);
    }
    __syncthreads();
#pragma unroll
    for (int s2 = 0; s2 < 2; ++s2) {
      short8 af[4], bfr[4];
      int kq = s2 * 4 + (lane >> 4);
#pragma unroll
      for (int m = 0; m < 4; ++m) {
        int row = wr * 64 + m * 16 + (lane & 15);
        af[m] = *(const short8*)(Asw + row * 64 + SWZ(row, kq) * 8);
      }
#pragma unroll
      for (int n = 0; n < 4; ++n) {
        int c = wc * 64 + n * 16 + (lane & 15);
        bfr[n] = *(const short8*)(Bsw + c * 64 + SWZ(c, kq) * 8);
      }
#pragma unroll
      for (int m = 0; m < 4; ++m)
#pragma unroll
        for (int n = 0; n < 4; ++n)
          acc[m][n] = __builtin_amdgcn_mfma_f32_16x16x32_bf16(af[m], bfr[n], acc[m][n], 0, 0, 0);
    }
  }

  // epilogue (C/D frag: col = lane&15, row = (lane>>4)*4 + reg)
#pragma unroll
  for (int m = 0; m < 4; ++m) {
#pragma unroll
    for (int j = 0; j < 4; ++j) {
      int gr = r0 + wr * 64 + m * 16 + (lane >> 4) * 4 + j;
      if (gr >= n_rows) continue;
      if (ACT == 0) {
#pragma unroll
        for (int n = 0; n < 4; ++n) {
          int gc = n0 + wc * 64 + n * 16 + (lane & 15);
          float v = acc[m][n][j] + bias[e * N + gc];
          Hout[(size_t)(row_base + gr) * N + gc] = bf16rne(gelu_fast(v));
        }
      } else {
        int tok = pair_token[row_base + gr];
        float w2 = pair_w[row_base + gr];
#pragma unroll
        for (int n = 0; n < 4; ++n) {
          int gc = n0 + wc * 64 + n * 16 + (lane & 15);
          float v = acc[m][n][j] + bias[e * N + gc];
          atomicAdd(&out[(size_t)tok * N + gc], w2 * v);
        }
      }
    }
  }
}

__global__ __launch_bounds__(256) void moe_gemm1(
    const unsigned short* __restrict__ Aall, const unsigned short* __restrict__ BT,
    const float* __restrict__ bias, const int* __restrict__ hdr,
    unsigned short* __restrict__ Hout)
{
  gemm_body<0>(Aall, BT, bias, hdr, Hout, nullptr, nullptr, nullptr,
               DD, HH, (MBLK * (HH / 128)) / 8);
}

__global__ __launch_bounds__(256) void moe_gemm2(
    const unsigned short* __restrict__ Aall, const unsigned short* __restrict__ BT,
    const float* __restrict__ bias, const int* __restrict__ hdr,
    const int* __restrict__ pair_token, const float* __restrict__ pair_w,
    float* __restrict__ out)
{
  gemm_body<1>(Aall, BT, bias, hdr, nullptr, pair_token, pair_w, out,
               HH, DD, (MBLK * (DD / 128)) / 8);
}

extern "C" void kernel_launch(void* const* d_in, const int* in_sizes, int n_in,
                              void* d_out, int out_size, void* d_ws, size_t ws_size,
                              hipStream_t stream) {
  const float* x  = (const float*)d_in[0];
  const float* rw = (const float*)d_in[1];
  const float* w1 = (const float*)d_in[2];
  const float* b1 = (const float*)d_in[3];
  const float* w2 = (const float*)d_in[4];
  const float* b2 = (const float*)d_in[5];
  float* out = (float*)d_out;

  // ws layout: hdr 4KB | te,tw,pt,pw 4x64KB | xg bf16[(P+256)*D] |
  //            h bf16[(P+256)*H] | wT bf16[E*D*H] (shared by w1T then w2T)
  char* ws = (char*)d_ws;
  const size_t OFF_TE = 4096;
  const size_t OFF_TW = OFF_TE + (size_t)NPAIR * 4;
  const size_t OFF_PT = OFF_TW + (size_t)NPAIR * 4;
  const size_t OFF_PW = OFF_PT + (size_t)NPAIR * 4;
  const size_t OFF_XG = OFF_PW + (size_t)NPAIR * 4;
  const size_t OFF_H  = OFF_XG + (size_t)(NPAIR + PADROWS) * DD * 2;
  const size_t OFF_WT = OFF_H + (size_t)(NPAIR + PADROWS) * HH * 2;
  const size_t NEEDED = OFF_WT + (size_t)NE * DD * HH * 2;
  if (ws_size < NEEDED) return;  // visible failure signal (zero output)

  int*   hdr        = (int*)ws;
  int*   te         = (int*)(ws + OFF_TE);
  float* tw         = (float*)(ws + OFF_TW);
  int*   pair_token = (int*)(ws + OFF_PT);
  float* pair_w     = (float*)(ws + OFF_PW);
  unsigned short* xg = (unsigned short*)(ws + OFF_XG);
  unsigned short* h  = (unsigned short*)(ws + OFF_H);
  unsigned short* wT = (unsigned short*)(ws + OFF_WT);

  hipMemsetAsync(d_ws, 0, 4096, stream);
  hipMemsetAsync(d_out, 0, (size_t)out_size * sizeof(float), stream);

  router_kernel<<<TT / 4, 256, 0, stream>>>(x, rw, hdr, te, tw);
  scan_kernel<<<1, 64, 0, stream>>>(hdr);
  assign_kernel<<<TT / 256, 256, 0, stream>>>(te, tw, hdr, pair_token, pair_w);
  copy_kernel<<<NPAIR / 4, 256, 0, stream>>>(x, pair_token, xg);

  // w1[e][D][H] -> w1T[e][H][D]
  transpose_bf16_kernel<<<dim3(HH / 64, DD / 64, NE), 256, 0, stream>>>(w1, wT, DD, HH);
  // GEMM1: grid 136 x 32 = 4352 blocks; 544/XCD = 17 supertiles exactly
  moe_gemm1<<<dim3(MBLK, HH / 128), 256, 0, stream>>>(xg, wT, b1, hdr, h);

  // w2[e][H][D] -> w2T[e][D][H]
  transpose_bf16_kernel<<<dim3(DD / 64, HH / 64, NE), 256, 0, stream>>>(w2, wT, HH, DD);
  // GEMM2: grid 136 x 8 = 1088 blocks; 136/XCD
  moe_gemm2<<<dim3(MBLK, DD / 128), 256, 0, stream>>>(
      h, wT, b2, hdr, pair_token, pair_w, out);
}

// Round 19
// 758.609 us; speedup vs baseline: 1.1259x; 1.0052x over previous
//
#include <hip/hip_runtime.h>
#include <hip/hip_bf16.h>

// SparseMoE: x[8,1024,1024] fp32, router[1024,8], w1[8,1024,4096], b1, w2[8,4096,1024], b2.
// Pipeline: router -> scan (PARALLEL offsets + tile map) -> assign -> copy ->
// transpose w1 -> GEMM1 (128^2 BK=64 single-buf, supertile XCD order, fast-GELU -> h bf16)
// -> transpose w2 -> GEMM2 (same structure, atomicAdd into out).
// [r14 GEMM configuration — session best 761-762 us, reproduced twice]

#define TT 8192
#define DD 1024
#define HH 4096
#define NE 8
#define NPAIR (TT * 2)          // 16384
#define PADROWS 256
#define MBLK (NPAIR / 128 + NE) // 136: max 128-row tiles

typedef __attribute__((ext_vector_type(4))) float f32x4;
typedef __attribute__((ext_vector_type(8))) short short8;
typedef __attribute__((ext_vector_type(4))) unsigned short u16x4;

__device__ __forceinline__ unsigned short bf16rne(float f) {
  union { float f; unsigned u; } v; v.f = f;
  unsigned r = v.u + 0x7FFFu + ((v.u >> 16) & 1u);
  return (unsigned short)(r >> 16);
}

// tanh-form GELU (|err| <= ~3e-3 vs exact; invisible under bf16 h + GEMM2 contraction)
__device__ __forceinline__ float gelu_fast(float x) {
  float y = 0.7978845608028654f * (x + 0.044715f * x * x * x);
  float e = __expf(2.0f * y);
  float th = 1.0f - 2.0f / (e + 1.0f);
  return 0.5f * x * (1.0f + th);
}

// 16B-granule swizzle within a [rows][8-granule] LDS tile; involution.
#define SWZ(r, kb) ((kb) ^ (((r) + ((r) >> 3)) & 7))

// hdr ints: [0..7] counts, [8..15] fill, [16..24] offsets, [25] tcnt,
// [32..167] tile_e, [168..303] tile_r0
#define HDR_OFFS 16
#define HDR_TCNT 25
#define HDR_TE   32
#define HDR_TR   168

// ---------------- router: logits (fp64 accum), softmax-top2, counts ----------------
__global__ __launch_bounds__(256) void router_kernel(
    const float* __restrict__ x, const float* __restrict__ rw,
    int* __restrict__ hdr, int* __restrict__ te, float* __restrict__ tw)
{
  int t = blockIdx.x * 4 + (threadIdx.x >> 6);
  int lane = threadIdx.x & 63;
  const float* xr = x + (size_t)t * DD;
  double acc[NE];
#pragma unroll
  for (int e = 0; e < NE; ++e) acc[e] = 0.0;
  for (int i = 0; i < DD / 64; ++i) {
    int d = i * 64 + lane;
    float xv = xr[d];
    f32x4 r0 = *(const f32x4*)(rw + (size_t)d * NE);
    f32x4 r1 = *(const f32x4*)(rw + (size_t)d * NE + 4);
#pragma unroll
    for (int e = 0; e < 4; ++e) acc[e] += (double)xv * (double)r0[e];
#pragma unroll
    for (int e = 0; e < 4; ++e) acc[4 + e] += (double)xv * (double)r1[e];
  }
#pragma unroll
  for (int off = 32; off > 0; off >>= 1) {
#pragma unroll
    for (int e = 0; e < NE; ++e) acc[e] += __shfl_xor(acc[e], off);
  }
  if (lane == 0) {
    float l[NE];
#pragma unroll
    for (int e = 0; e < NE; ++e) l[e] = (float)acc[e];
    int bi = 0; float bv = l[0]; int si = -1; float sv = -3.0e38f;
#pragma unroll
    for (int e = 1; e < NE; ++e) {
      float v = l[e];
      if (v > bv) { sv = bv; si = bi; bv = v; bi = e; }
      else if (v > sv) { sv = v; si = e; }
    }
    float es = expf(sv - bv);
    float wb = 1.0f / (1.0f + es);
    float ws2 = es / (1.0f + es);
    te[2 * t] = bi; te[2 * t + 1] = si;
    tw[2 * t] = wb; tw[2 * t + 1] = ws2;
    atomicAdd(&hdr[bi], 1);
    atomicAdd(&hdr[si], 1);
  }
}

// ---------------- scan (parallel): offsets + M-tile map ----------------
__global__ __launch_bounds__(256) void scan_kernel(int* __restrict__ hdr) {
  __shared__ int cnt[NE], offs[NE + 1], tstart[NE + 1];
  const int tid = threadIdx.x;
  if (tid < NE) cnt[tid] = hdr[tid];
  __syncthreads();
  if (tid == 0) {
    int s = 0, t = 0;
#pragma unroll
    for (int e = 0; e < NE; ++e) {
      offs[e] = s;   s += cnt[e];
      tstart[e] = t; t += (cnt[e] + 127) >> 7;
    }
    offs[NE] = s;
    tstart[NE] = t;
    hdr[HDR_TCNT] = t;
  }
  __syncthreads();
  if (tid < NE + 1) hdr[HDR_OFFS + tid] = offs[tid];
  if (tid < NE) hdr[8 + tid] = 0;                 // zero fill counters
  const int tcnt = tstart[NE];
  for (int i = tid; i < tcnt; i += 256) {
    int e = 0;
#pragma unroll
    for (int k = 0; k < NE - 1; ++k) if (i >= tstart[k + 1]) e = k + 1;
    hdr[HDR_TE + i] = e;
    hdr[HDR_TR + i] = (i - tstart[e]) * 128;
  }
}

// ---------------- assign: wave-aggregated slot allocation ----------------
__global__ __launch_bounds__(256) void assign_kernel(
    const int* __restrict__ te, const float* __restrict__ tw, int* __restrict__ hdr,
    int* __restrict__ pair_token, float* __restrict__ pair_w)
{
  int lane = threadIdx.x & 63;
  int t = blockIdx.x * 256 + threadIdx.x;
  int e0 = te[2 * t], e1 = te[2 * t + 1];
  const int* offs = hdr + HDR_OFFS;
  unsigned long long below = (1ull << lane) - 1ull;
  int slot0 = 0, slot1 = 0;
#pragma unroll
  for (int e = 0; e < NE; ++e) {
    unsigned long long m0 = __ballot(e0 == e);
    unsigned long long m1 = __ballot(e1 == e);
    int cnt = __popcll(m0) + __popcll(m1);
    int base = 0;
    if (lane == 0 && cnt) base = atomicAdd(&hdr[8 + e], cnt);
    base = __shfl(base, 0);
    int s = offs[e] + base;
    if (e0 == e) slot0 = s + __popcll(m0 & below);
    if (e1 == e) slot1 = s + __popcll(m0) + __popcll(m1 & below);
  }
  pair_token[slot0] = t; pair_w[slot0] = tw[2 * t];
  pair_token[slot1] = t; pair_w[slot1] = tw[2 * t + 1];
}

// ---------------- copy: one wave per pair, x[tok] f32 -> xg[pair] bf16 ----------------
__global__ __launch_bounds__(256) void copy_kernel(
    const float* __restrict__ x, const int* __restrict__ pair_token,
    unsigned short* __restrict__ xg)
{
  int p = (blockIdx.x * 256 + threadIdx.x) >> 6;
  int lane = threadIdx.x & 63;
  int tok = pair_token[p];
  const f32x4* xr = (const f32x4*)(x + (size_t)tok * DD);
  unsigned short* d = xg + (size_t)p * DD;
#pragma unroll
  for (int i = 0; i < 4; ++i) {
    int idx = i * 64 + lane;
    f32x4 v = xr[idx];
    u16x4 b;
#pragma unroll
    for (int j = 0; j < 4; ++j) b[j] = bf16rne(v[j]);
    *(u16x4*)(d + idx * 4) = b;
  }
}

// ---------------- transpose+convert: W[e][K][N] f32 -> WT[e][N][K] bf16 ----------------
__global__ __launch_bounds__(256) void transpose_bf16_kernel(
    const float* __restrict__ W, unsigned short* __restrict__ WT, int K, int N)
{
  __shared__ unsigned short t[64][72];
  const float* src = W + (size_t)blockIdx.z * K * N;
  unsigned short* dst = WT + (size_t)blockIdx.z * N * K;
  const int K0 = blockIdx.y * 64, N0 = blockIdx.x * 64;
  const int tid = threadIdx.x;
  const int c = (tid & 15) * 4;
#pragma unroll
  for (int p = 0; p < 4; ++p) {
    int r = (tid >> 4) + p * 16;
    f32x4 v = *(const f32x4*)(src + (size_t)(K0 + r) * N + N0 + c);
    u16x4 b;
#pragma unroll
    for (int j = 0; j < 4; ++j) b[j] = bf16rne(v[j]);
    *(u16x4*)&t[r][c] = b;
  }
  __syncthreads();
  const int n = tid >> 2;
  const int k0 = (tid & 3) * 16;
  __align__(16) unsigned short tmp[16];
#pragma unroll
  for (int i = 0; i < 16; ++i) tmp[i] = t[k0 + i][n];
  unsigned short* dp = dst + (size_t)(N0 + n) * K + K0 + k0;
  *(u16x4*)(dp + 0)  = *(u16x4*)(tmp + 0);
  *(u16x4*)(dp + 4)  = *(u16x4*)(tmp + 4);
  *(u16x4*)(dp + 8)  = *(u16x4*)(tmp + 8);
  *(u16x4*)(dp + 12) = *(u16x4*)(tmp + 12);
}

// ---------------- grouped GEMM body: 128x128, BK=64, 4 waves, single-buf --------
// Chunked-supertile XCD ordering: supertile = 8 m-tiles x 4 n-tiles = 32 blocks
// (A 2MB + B 1MB fits one XCD's 4MB L2); supertiles contiguous per XCD.
template <int ACT>
__device__ __forceinline__ void gemm_body(
    const unsigned short* __restrict__ Aall,
    const unsigned short* __restrict__ BT,
    const float* __restrict__ bias,
    const int* __restrict__ hdr,
    unsigned short* __restrict__ Hout,
    const int* __restrict__ pair_token,
    const float* __restrict__ pair_w,
    float* __restrict__ out,
    int K, int N, int XPB)
{
  const int orig = blockIdx.x + MBLK * blockIdx.y;
  const int xcd = orig & 7, loc = orig >> 3;
  const int idx = xcd * XPB + loc;
  const int st = idx >> 5, w = idx & 31;
  const int mx = (st % 17) * 8 + (w & 7);
  const int ny = (st / 17) * 4 + (w >> 3);

  if (mx >= hdr[HDR_TCNT]) return;
  const int e = hdr[HDR_TE + mx];
  const int r0 = hdr[HDR_TR + mx];
  const int* offs = hdr + HDR_OFFS;
  const int row_base = offs[e];
  const int n_rows = offs[e + 1] - row_base;
  const int n0 = ny * 128;

  const unsigned short* A = Aall + (size_t)row_base * K;
  const unsigned short* B = BT + (size_t)e * N * K;

  __shared__ __align__(16) unsigned short Asw[128 * 64];
  __shared__ __align__(16) unsigned short Bsw[128 * 64];

  const int tid = threadIdx.x;
  const int lane = tid & 63;
  const int wv = tid >> 6;
  const int wr = wv >> 1, wc = wv & 1;

  f32x4 acc[4][4] = {};

  for (int k0 = 0; k0 < K; k0 += 64) {
    if (k0) __syncthreads();
#pragma unroll
    for (int p = 0; p < 4; ++p) {
      int s = p * 256 + tid;
      int row = s >> 3;
      int kb = SWZ(row, s & 7);
      __builtin_amdgcn_global_load_lds(
          (const __attribute__((address_space(1))) void*)(A + (size_t)(r0 + row) * K + k0 + kb * 8),
          (__attribute__((address_space(3))) void*)(Asw + s * 8), 16, 0, 0);
    }
#pragma unroll
    for (int p = 0; p < 4; ++p) {
      int s = p * 256 + tid;
      int row = s >> 3;
      int kb = SWZ(row, s & 7);
      __builtin_amdgcn_global_load_lds(
          (const __attribute__((address_space(1))) void*)(B + (size_t)(n0 + row) * K + k0 + kb * 8),
          (__attribute__((address_space(3))) void*)(Bsw + s * 8), 16, 0, 0);
    }
    __syncthreads();
#pragma unroll
    for (int s2 = 0; s2 < 2; ++s2) {
      short8 af[4], bfr[4];
      int kq = s2 * 4 + (lane >> 4);
#pragma unroll
      for (int m = 0; m < 4; ++m) {
        int row = wr * 64 + m * 16 + (lane & 15);
        af[m] = *(const short8*)(Asw + row * 64 + SWZ(row, kq) * 8);
      }
#pragma unroll
      for (int n = 0; n < 4; ++n) {
        int c = wc * 64 + n * 16 + (lane & 15);
        bfr[n] = *(const short8*)(Bsw + c * 64 + SWZ(c, kq) * 8);
      }
#pragma unroll
      for (int m = 0; m < 4; ++m)
#pragma unroll
        for (int n = 0; n < 4; ++n)
          acc[m][n] = __builtin_amdgcn_mfma_f32_16x16x32_bf16(af[m], bfr[n], acc[m][n], 0, 0, 0);
    }
  }

  // epilogue (C/D frag: col = lane&15, row = (lane>>4)*4 + reg)
#pragma unroll
  for (int m = 0; m < 4; ++m) {
#pragma unroll
    for (int j = 0; j < 4; ++j) {
      int gr = r0 + wr * 64 + m * 16 + (lane >> 4) * 4 + j;
      if (gr >= n_rows) continue;
      if (ACT == 0) {
#pragma unroll
        for (int n = 0; n < 4; ++n) {
          int gc = n0 + wc * 64 + n * 16 + (lane & 15);
          float v = acc[m][n][j] + bias[e * N + gc];
          Hout[(size_t)(row_base + gr) * N + gc] = bf16rne(gelu_fast(v));
        }
      } else {
        int tok = pair_token[row_base + gr];
        float w2 = pair_w[row_base + gr];
#pragma unroll
        for (int n = 0; n < 4; ++n) {
          int gc = n0 + wc * 64 + n * 16 + (lane & 15);
          float v = acc[m][n][j] + bias[e * N + gc];
          atomicAdd(&out[(size_t)tok * N + gc], w2 * v);
        }
      }
    }
  }
}

__global__ __launch_bounds__(256) void moe_gemm1(
    const unsigned short* __restrict__ Aall, const unsigned short* __restrict__ BT,
    const float* __restrict__ bias, const int* __restrict__ hdr,
    unsigned short* __restrict__ Hout)
{
  gemm_body<0>(Aall, BT, bias, hdr, Hout, nullptr, nullptr, nullptr,
               DD, HH, (MBLK * (HH / 128)) / 8);
}

__global__ __launch_bounds__(256) void moe_gemm2(
    const unsigned short* __restrict__ Aall, const unsigned short* __restrict__ BT,
    const float* __restrict__ bias, const int* __restrict__ hdr,
    const int* __restrict__ pair_token, const float* __restrict__ pair_w,
    float* __restrict__ out)
{
  gemm_body<1>(Aall, BT, bias, hdr, nullptr, pair_token, pair_w, out,
               HH, DD, (MBLK * (DD / 128)) / 8);
}

extern "C" void kernel_launch(void* const* d_in, const int* in_sizes, int n_in,
                              void* d_out, int out_size, void* d_ws, size_t ws_size,
                              hipStream_t stream) {
  const float* x  = (const float*)d_in[0];
  const float* rw = (const float*)d_in[1];
  const float* w1 = (const float*)d_in[2];
  const float* b1 = (const float*)d_in[3];
  const float* w2 = (const float*)d_in[4];
  const float* b2 = (const float*)d_in[5];
  float* out = (float*)d_out;

  // ws layout: hdr 4KB | te,tw,pt,pw 4x64KB | xg bf16[(P+256)*D] |
  //            h bf16[(P+256)*H] | wT bf16[E*D*H] (shared by w1T then w2T)
  char* ws = (char*)d_ws;
  const size_t OFF_TE = 4096;
  const size_t OFF_TW = OFF_TE + (size_t)NPAIR * 4;
  const size_t OFF_PT = OFF_TW + (size_t)NPAIR * 4;
  const size_t OFF_PW = OFF_PT + (size_t)NPAIR * 4;
  const size_t OFF_XG = OFF_PW + (size_t)NPAIR * 4;
  const size_t OFF_H  = OFF_XG + (size_t)(NPAIR + PADROWS) * DD * 2;
  const size_t OFF_WT = OFF_H + (size_t)(NPAIR + PADROWS) * HH * 2;
  const size_t NEEDED = OFF_WT + (size_t)NE * DD * HH * 2;
  if (ws_size < NEEDED) return;  // visible failure signal (zero output)

  int*   hdr        = (int*)ws;
  int*   te         = (int*)(ws + OFF_TE);
  float* tw         = (float*)(ws + OFF_TW);
  int*   pair_token = (int*)(ws + OFF_PT);
  float* pair_w     = (float*)(ws + OFF_PW);
  unsigned short* xg = (unsigned short*)(ws + OFF_XG);
  unsigned short* h  = (unsigned short*)(ws + OFF_H);
  unsigned short* wT = (unsigned short*)(ws + OFF_WT);

  hipMemsetAsync(d_ws, 0, 4096, stream);
  hipMemsetAsync(d_out, 0, (size_t)out_size * sizeof(float), stream);

  router_kernel<<<TT / 4, 256, 0, stream>>>(x, rw, hdr, te, tw);
  scan_kernel<<<1, 256, 0, stream>>>(hdr);
  assign_kernel<<<TT / 256, 256, 0, stream>>>(te, tw, hdr, pair_token, pair_w);
  copy_kernel<<<NPAIR / 4, 256, 0, stream>>>(x, pair_token, xg);

  // w1[e][D][H] -> w1T[e][H][D]
  transpose_bf16_kernel<<<dim3(HH / 64, DD / 64, NE), 256, 0, stream>>>(w1, wT, DD, HH);
  // GEMM1: grid 136 x 32 = 4352 blocks; 544/XCD = 17 supertiles exactly
  moe_gemm1<<<dim3(MBLK, HH / 128), 256, 0, stream>>>(xg, wT, b1, hdr, h);

  // w2[e][H][D] -> w2T[e][D][H]
  transpose_bf16_kernel<<<dim3(DD / 64, HH / 64, NE), 256, 0, stream>>>(w2, wT, HH, DD);
  // GEMM2: grid 136 x 8 = 1088 blocks; 136/XCD
  moe_gemm2<<<dim3(MBLK, DD / 128), 256, 0, stream>>>(
      h, wT, b2, hdr, pair_token, pair_w, out);
}